// Round 14
// baseline (35.933 us; speedup 1.0000x reference)
//
#include <hip/hip_runtime.h>
#include <stdint.h>

#define NUM_CLASSES 20
#define NUM_GRID    7
#define NCELL   3136
#define NCAND   6272
#define CPB     49
#define KPB     98
#define NW      8
#define TPB2    512
#define NCHUNK  98

// ---- workspace layout (bytes) ----
#define WS_SCORE     0         // f32[6272]            25088
#define WS_CELLBOX   25088     // f32[3136*4]          50176
#define WS_CELLLAB   75264     // f32[3136]            12544
#define WS_KEYLO     87808     // u32[6272]            25088

// monotone float -> sortable u32 (ascending float == ascending u32)
__device__ __forceinline__ unsigned fkey(float f) {
    unsigned u = __float_as_uint(f);
    return (u & 0x80000000u) ? ~u : (u | 0x80000000u);
}

__device__ __forceinline__ float cand_score(const float* q) {
    float conf = q[4];
    float m = __fmul_rn(q[5], conf);
    #pragma unroll
    for (int k = 1; k < NUM_CLASSES; ++k)
        m = fmaxf(m, __fmul_rn(q[5 + k], conf));
    return m;
}

__device__ __forceinline__ float iou_rn(float4 a, float4 b) {
    float xx1 = fmaxf(a.x, b.x), yy1 = fmaxf(a.y, b.y);
    float xx2 = fminf(a.z, b.z), yy2 = fminf(a.w, b.w);
    float w = fmaxf(__fsub_rn(xx2, xx1), 0.0f);
    float h = fmaxf(__fsub_rn(yy2, yy1), 0.0f);
    float inter = __fmul_rn(w, h);
    float aa = __fmul_rn(__fsub_rn(a.z, a.x), __fsub_rn(a.w, a.y));
    float ab = __fmul_rn(__fsub_rn(b.z, b.x), __fsub_rn(b.w, b.y));
    float denom = __fadd_rn(__fsub_rn(__fadd_rn(aa, ab), inter), 1e-9f);
    return __fdiv_rn(inter, denom);
}

// K1: pure decode, 49 blocks x 64, coalesced float4 staging -> LDS decode.
__global__ void __launch_bounds__(64) k_decode(
        const float* __restrict__ in,
        float* __restrict__ score,
        float* __restrict__ cellBox,
        float* __restrict__ cellLabel,
        unsigned* __restrict__ keyLo) {
    __shared__ float4 raw4[800];                   // 64 cells * 50 f = 12.8 KB
    const int lane = (int)threadIdx.x;
    const int bid  = (int)blockIdx.x;

    const float4* src = (const float4*)in + bid * 800;
    #pragma unroll
    for (int t = 0; t < 13; ++t) {
        int j = t * 64 + lane;
        if (j < 800) raw4[j] = src[j];
    }
    __syncthreads();

    const float* p = (const float*)raw4 + lane * 50;
    int cell = bid * 64 + lane;
    float s0 = cand_score(p);
    float s1 = cand_score(p + 25);
    int best = (s1 > s0) ? 1 : 0;                  // first-occurrence argmax
    const float* q = p + best * 25;

    int lab = 0; float bv = q[5];
    #pragma unroll
    for (int k = 1; k < NUM_CLASSES; ++k)
        if (q[5 + k] > bv) { bv = q[5 + k]; lab = k; }

    int rc = cell % (NUM_GRID * NUM_GRID);
    int r = rc / NUM_GRID, c = rc % NUM_GRID;
    float x  = __fdiv_rn(__fadd_rn(q[0], (float)r), 7.0f);
    float y  = __fdiv_rn(__fadd_rn(q[1], (float)c), 7.0f);
    float hw = __fmul_rn(q[2], 0.5f);
    float hh = __fmul_rn(q[3], 0.5f);
    *(float4*)(cellBox + cell * 4) =
        make_float4(__fsub_rn(x, hw), __fsub_rn(y, hh),
                    __fadd_rn(x, hw), __fadd_rn(y, hh));
    cellLabel[cell] = (float)(lab + 1);
    score[cell * 2 + 0] = s0;
    score[cell * 2 + 1] = s1;
    keyLo[cell * 2 + 0] = fkey((s0 > 0.5f) ? -s0 : __builtin_inff());
    keyLo[cell * 2 + 1] = fkey((s1 > 0.5f) ? -s1 : __builtin_inff());
}

// K2: 98 blocks x 512. Compaction-rank (R13-proven) + in-block NMS over the
// block's 1-2 batches (R11-proven 5x8-wave loop, inputs from WS not raw) +
// scatter. keep lives in LDS only.
__global__ void __launch_bounds__(TPB2) k_all(
        const unsigned* __restrict__ keyLo,
        const float* __restrict__ score,
        const float* __restrict__ cellBox,
        const float* __restrict__ cellLabel,
        float* __restrict__ out) {
    __shared__ unsigned vkey[NCAND];               // compacted valid keys
    __shared__ unsigned long long mkey[NW][KPB];
    __shared__ unsigned long long skey[NW][KPB];
    __shared__ float    lkeep[2][KPB];
    __shared__ unsigned chunkCnt[NCHUNK];
    __shared__ unsigned chunkOff[NCHUNK];
    __shared__ unsigned prefVOwn[64];
    __shared__ unsigned rankPart[NW][64];
    __shared__ unsigned nV_s;

    const int tid  = (int)threadIdx.x;
    const int lane = tid & 63;
    const int w    = tid >> 6;
    const int ib   = (int)blockIdx.x;              // 0..97
    const int i0   = ib * 64;
    const int b0   = i0 / KPB;
    const bool need2 = ((i0 + 63) / KPB) > b0;

    if (tid < 2 * KPB) ((float*)lkeep)[tid] = 0.0f;

    // ---- coalesced key loads: wave w holds chunks w+8k ----
    unsigned kreg[13];
    #pragma unroll
    for (int k = 0; k < 13; ++k) {
        int ch = NW * k + w;
        kreg[k] = (ch < NCHUNK) ? keyLo[ch * 64 + lane] : 0xFFFFFFFFu;
    }
    #pragma unroll
    for (int k = 0; k < 13; ++k) {
        int ch = NW * k + w;
        if (ch < NCHUNK) {
            unsigned long long bal = __ballot(kreg[k] < 0x80000000u);
            if (lane == 0) chunkCnt[ch] = (unsigned)__popcll(bal);
        }
    }
    __syncthreads();                               // B1
    if (tid < NCHUNK) {
        unsigned off = 0;
        for (int t = 0; t < tid; ++t) off += chunkCnt[t];
        chunkOff[tid] = off;
        if (tid == NCHUNK - 1) nV_s = off + chunkCnt[NCHUNK - 1];
    }
    __syncthreads();                               // B2
    #pragma unroll
    for (int k = 0; k < 13; ++k) {
        int ch = NW * k + w;
        if (ch < NCHUNK) {
            bool val = kreg[k] < 0x80000000u;
            unsigned long long bal = __ballot(val);
            unsigned pos = chunkOff[ch] +
                (unsigned)__popcll(bal & ((1ull << lane) - 1ull));
            if (val) vkey[pos] = kreg[k];
            if (ch == ib) prefVOwn[lane] = pos;    // #valid with idx < own i
        }
    }

    // ---- NMS: 40 tasks (2 batches x 20 labels), 5 serial per wave ----
    for (int it = 0; it < 5; ++it) {
        int task = it * NW + w;                    // 0..39
        int bb = task / NUM_CLASSES;
        int L  = task - bb * NUM_CLASSES + 1;
        bool alive = (bb == 0) || need2;
        int base = (b0 + bb) * KPB;
        bool v0 = false, v1 = false;
        unsigned long long key0 = 0, key1 = 0;
        if (alive) {
            unsigned kl0 = keyLo[base + lane];
            v0 = (kl0 < 0x80000000u) &&
                 (cellLabel[(base + lane) >> 1] == (float)L);
            key0 = ((unsigned long long)kl0 << 32) | (unsigned)(base + lane);
            if (lane + 64 < KPB) {
                unsigned kl1 = keyLo[base + lane + 64];
                v1 = (kl1 < 0x80000000u) &&
                     (cellLabel[(base + lane + 64) >> 1] == (float)L);
                key1 = ((unsigned long long)kl1 << 32) | (unsigned)(base + lane + 64);
            }
        }
        unsigned long long bal0 = __ballot(v0), bal1 = __ballot(v1);
        int n0 = (int)__popcll(bal0);
        int n  = n0 + (int)__popcll(bal1);
        unsigned long long below = (1ull << lane) - 1ull;
        if (v0) mkey[w][__popcll(bal0 & below)] = key0;
        if (v1) mkey[w][n0 + __popcll(bal1 & below)] = key1;
        __syncthreads();                           // uniform (5 iters all waves)
        if (n > 0) {
            for (int s = 0; s < 2; ++s) {
                int j = lane + s * 64;
                if (j < n) {
                    unsigned long long kj = mkey[w][j];
                    int rr = 0;
                    for (int i2 = 0; i2 < n; ++i2) rr += (mkey[w][i2] < kj) ? 1 : 0;
                    skey[w][rr] = kj;              // rank-by-count == stable sort
                }
            }
        }
        __syncthreads();                           // uniform
        if (n > 0) {
            float4 box0 = make_float4(0.f, 0.f, 0.f, 0.f), box1 = box0;
            int t0 = 0, t1 = 0, keep0 = 0, keep1 = 0;
            if (lane < n) {
                int idx = (int)(unsigned)skey[w][lane];
                t0 = idx - base;
                box0 = *(const float4*)(cellBox + (idx >> 1) * 4);
                keep0 = 1;
            }
            if (lane + 64 < n) {
                int idx = (int)(unsigned)skey[w][lane + 64];
                t1 = idx - base;
                box1 = *(const float4*)(cellBox + (idx >> 1) * 4);
                keep1 = 1;
            }
            for (int g = 0; g < n; ++g) {
                int srcl = g & 63;
                int kg = __shfl((g < 64) ? keep0 : keep1, srcl);
                if (kg) {
                    float4 s4 = (g < 64) ? box0 : box1;
                    float4 bi;
                    bi.x = __shfl(s4.x, srcl); bi.y = __shfl(s4.y, srcl);
                    bi.z = __shfl(s4.z, srcl); bi.w = __shfl(s4.w, srcl);
                    if (keep0 && lane > g)      { if (iou_rn(bi, box0) > 0.3f) keep0 = 0; }
                    if (keep1 && lane + 64 > g) { if (iou_rn(bi, box1) > 0.3f) keep1 = 0; }
                }
            }
            if (keep0) lkeep[bb][t0] = 1.0f;
            if (keep1) lkeep[bb][t1] = 1.0f;
        }
    }
    __syncthreads();                               // B3: vkey/prefVOwn/lkeep final

    // ---- rank own 64 candidates vs compacted valid keys (R13-proven) ----
    const int iG = i0 + lane;
    unsigned kiLo = keyLo[iG];
    unsigned ci   = prefVOwn[lane];
    {
        unsigned nV = nV_s;
        int cs = ((int)nV + NW - 1) / NW;
        int j0 = w * cs;
        int j1 = min((int)nV, j0 + cs);
        unsigned acc = 0;
        #pragma unroll 8
        for (int j = j0; j < j1; ++j) {
            unsigned kj = vkey[j];                 // wave-uniform broadcast read
            acc += (kj < kiLo) ? 1u : 0u;
            acc += (kj == kiLo && (unsigned)j < ci) ? 1u : 0u;  // stable tie-break
        }
        rankPart[w][lane] = acc;
    }
    __syncthreads();                               // B4
    if (tid < 64) {
        unsigned r;
        if (kiLo < 0x80000000u) {
            r = 0;
            #pragma unroll
            for (int w2 = 0; w2 < NW; ++w2) r += rankPart[w2][lane];
        } else {
            r = nV_s + (unsigned)iG - ci;          // closed form for invalid
        }
        int bg   = iG / KPB;
        int il   = iG - bg * KPB;
        int bb2  = bg - b0;                        // 0 or 1
        int cell = iG >> 1;
        out[r] = (float)bg;                        // batch id
        float4 bx = *(const float4*)(cellBox + cell * 4);
        *(float4*)(out + NCAND + r * 4) = bx;
        out[NCAND * 5 + r] = cellLabel[cell];
        out[NCAND * 6 + r] = score[iG];
        out[NCAND * 7 + r] = lkeep[bb2][il];
    }
}

extern "C" void kernel_launch(void* const* d_in, const int* in_sizes, int n_in,
                              void* d_out, int out_size, void* d_ws, size_t ws_size,
                              hipStream_t stream) {
    const float* in = (const float*)d_in[0];
    char* ws = (char*)d_ws;
    float*    score     = (float*)(ws + WS_SCORE);
    float*    cellBox   = (float*)(ws + WS_CELLBOX);
    float*    cellLabel = (float*)(ws + WS_CELLLAB);
    unsigned* keyLo     = (unsigned*)(ws + WS_KEYLO);
    float* out = (float*)d_out;

    k_decode<<<CPB, 64, 0, stream>>>(in, score, cellBox, cellLabel, keyLo);
    k_all<<<NCHUNK, TPB2, 0, stream>>>(keyLo, score, cellBox, cellLabel, out);
}

// Round 15
// 30.811 us; speedup vs baseline: 1.1663x; 1.1663x over previous
//
#include <hip/hip_runtime.h>
#include <stdint.h>

#define NUM_CLASSES 20
#define NUM_GRID    7
#define NCELL   3136
#define NCAND   6272
#define NGROUP  1280
#define CPB     49
#define KPB     98
#define NJT     8
#define JCELLS  392                     // cells per j-tile
#define JTILE   784                     // candidates per j-tile
#define RCELLS  98                      // cells per stage round
#define NRND    4                       // rounds per j-tile

#define NDECB   49
#define B_RANK0 NDECB                   // rank blocks [49, 833)
#define B_NMS0  (NDECB + JTILE)         // nms blocks [833, 2113)
#define NBLK_K1 (NDECB + JTILE + NGROUP)

// ---- workspace layout (bytes) ----
#define WS_SCORE     0         // f32[6272]            25088
#define WS_CELLBOX   25088     // f32[3136*4]          50176
#define WS_CELLLAB   75264     // f32[3136]            12544
#define WS_KEEP      87808     // f32[6272]            25088
#define WS_RANKP     112896    // u32[8*6272]         200704

__device__ __forceinline__ unsigned fkey(float f) {
    unsigned u = __float_as_uint(f);
    return (u & 0x80000000u) ? ~u : (u | 0x80000000u);
}

__device__ __forceinline__ float cand_score(const float* q) {
    float conf = q[4];
    float m = __fmul_rn(q[5], conf);
    #pragma unroll
    for (int k = 1; k < NUM_CLASSES; ++k)
        m = fmaxf(m, __fmul_rn(q[5 + k], conf));
    return m;
}

__device__ __forceinline__ float iou_rn(float4 a, float4 b) {
    float xx1 = fmaxf(a.x, b.x), yy1 = fmaxf(a.y, b.y);
    float xx2 = fminf(a.z, b.z), yy2 = fminf(a.w, b.w);
    float w = fmaxf(__fsub_rn(xx2, xx1), 0.0f);
    float h = fmaxf(__fsub_rn(yy2, yy1), 0.0f);
    float inter = __fmul_rn(w, h);
    float aa = __fmul_rn(__fsub_rn(a.z, a.x), __fsub_rn(a.w, a.y));
    float ab = __fmul_rn(__fsub_rn(b.z, b.x), __fsub_rn(b.w, b.y));
    float denom = __fadd_rn(__fsub_rn(__fadd_rn(aa, ab), inter), 1e-9f);
    return __fdiv_rn(inter, denom);
}

// K1: 2113 single-wave blocks (barriers free).
//  [0,49):    decode (staged float4) -> score, cellBox, cellLabel
//  [49,833):  rank: stage j-tile in 4 coalesced rounds, keys from LDS,
//             own key scattered, plain-store rankPart[jt][i]
//  [833,2113):nms (R10-verbatim): keepOrig, disjoint-complete per label
__global__ void __launch_bounds__(64) k_main(
        const float* __restrict__ in,
        float* __restrict__ score,
        float* __restrict__ cellBox,
        float* __restrict__ cellLabel,
        float* __restrict__ keepOrig,
        unsigned* __restrict__ rankPart) {
    __shared__ union SMem {
        float4 draw4[800];                         // decode: 64 cells (12.8 KB)
        struct {                                   // rank: 25.9 KB
            float4 raw4[1225];                     // 98 cells staged / round
            unsigned long long jkey[JTILE];        // 784 j-keys
        } r;
        struct {                                   // nms: ~13.5 KB
            float2 raw2[1225];
            unsigned long long lkey[KPB];
            float4 lbox[CPB];
            int    llab[CPB];
            float  lkeep[KPB];
            unsigned long long mkey[KPB];
            unsigned long long skey[KPB];
        } nms;
    } sm;

    const int bid  = (int)blockIdx.x;
    const int lane = (int)threadIdx.x;

    // ---------------- decode blocks ----------------
    if (bid < NDECB) {
        const float4* src = (const float4*)in + bid * 800;
        #pragma unroll
        for (int t = 0; t < 13; ++t) {
            int j = t * 64 + lane;
            if (j < 800) sm.draw4[j] = src[j];
        }
        __syncthreads();
        const float* p = (const float*)sm.draw4 + lane * 50;
        int cell = bid * 64 + lane;
        float s0 = cand_score(p);
        float s1 = cand_score(p + 25);
        int best = (s1 > s0) ? 1 : 0;              // first-occurrence argmax
        const float* q = p + best * 25;
        int lab = 0; float bv = q[5];
        #pragma unroll
        for (int k = 1; k < NUM_CLASSES; ++k)
            if (q[5 + k] > bv) { bv = q[5 + k]; lab = k; }
        int rc = cell % (NUM_GRID * NUM_GRID);
        int r = rc / NUM_GRID, c = rc % NUM_GRID;
        float x  = __fdiv_rn(__fadd_rn(q[0], (float)r), 7.0f);
        float y  = __fdiv_rn(__fadd_rn(q[1], (float)c), 7.0f);
        float hw = __fmul_rn(q[2], 0.5f);
        float hh = __fmul_rn(q[3], 0.5f);
        *(float4*)(cellBox + cell * 4) =
            make_float4(__fsub_rn(x, hw), __fsub_rn(y, hh),
                        __fadd_rn(x, hw), __fadd_rn(y, hh));
        cellLabel[cell] = (float)(lab + 1);
        score[cell * 2 + 0] = s0;
        score[cell * 2 + 1] = s1;
        return;
    }

    // ---------------- rank blocks ----------------
    if (bid < B_NMS0) {
        int rb = bid - B_RANK0;
        int ib = rb >> 3;                          // 0..97
        int jt = rb & 7;                           // 0..7

        for (int rr = 0; rr < NRND; ++rr) {
            __syncthreads();                       // protect raw4 from prior readers
            const float4* src4 = (const float4*)in + jt * 4900 + rr * 1225;
            for (int t = lane; t < 1225; t += 64) sm.r.raw4[t] = src4[t];
            __syncthreads();                       // staging visible
            int cand0 = (jt * JCELLS + rr * RCELLS) * 2;
            for (int c = lane; c < 2 * RCELLS; c += 64) {
                const float* q = (const float*)sm.r.raw4 + (c >> 1) * 50 + (c & 1) * 25;
                float s = cand_score(q);
                float kf = (s > 0.5f) ? -s : __builtin_inff();
                sm.r.jkey[rr * 2 * RCELLS + c] =
                    ((unsigned long long)fkey(kf) << 32) | (unsigned)(cand0 + c);
            }
        }
        // own key (scattered, 1 candidate per lane)
        int i = ib * 64 + lane;
        unsigned long long my;
        {
            const float* q = in + (i >> 1) * 50 + (i & 1) * 25;
            float s = cand_score(q);
            float kf = (s > 0.5f) ? -s : __builtin_inff();
            my = ((unsigned long long)fkey(kf) << 32) | (unsigned)i;
        }
        __syncthreads();                           // jkey complete

        unsigned r = 0;
        #pragma unroll 8
        for (int j = 0; j < JTILE; ++j)
            r += (sm.r.jkey[j] < my) ? 1u : 0u;
        rankPart[jt * NCAND + i] = r;              // plain store, sole writer
        return;
    }

    // ---------------- nms blocks (R10-verbatim) ----------------
    int g = bid - B_NMS0;
    int b = g / NUM_CLASSES;
    int L = g % NUM_CLASSES + 1;
    int base = b * KPB;

    const float2* src = (const float2*)(in + b * (CPB * 50));
    for (int t = lane; t < 1225; t += 64) sm.nms.raw2[t] = src[t];
    sm.nms.lkeep[lane] = 0.0f;
    if (lane + 64 < KPB) sm.nms.lkeep[lane + 64] = 0.0f;
    __syncthreads();

    if (lane < CPB) {
        const float* p = (const float*)sm.nms.raw2 + lane * 50;
        float s0 = cand_score(p);
        float s1 = cand_score(p + 25);
        int best = (s1 > s0) ? 1 : 0;
        const float* q = p + best * 25;
        int lab = 0; float bv = q[5];
        #pragma unroll
        for (int k = 1; k < NUM_CLASSES; ++k)
            if (q[5 + k] > bv) { bv = q[5 + k]; lab = k; }
        int r = lane / NUM_GRID, c = lane % NUM_GRID;
        float x  = __fdiv_rn(__fadd_rn(q[0], (float)r), 7.0f);
        float y  = __fdiv_rn(__fadd_rn(q[1], (float)c), 7.0f);
        float hw = __fmul_rn(q[2], 0.5f);
        float hh = __fmul_rn(q[3], 0.5f);
        sm.nms.lbox[lane] = make_float4(__fsub_rn(x, hw), __fsub_rn(y, hh),
                                        __fadd_rn(x, hw), __fadd_rn(y, hh));
        sm.nms.llab[lane] = lab + 1;
        {
            float kf = (s0 > 0.5f) ? -s0 : __builtin_inff();
            sm.nms.lkey[lane * 2] =
                ((unsigned long long)fkey(kf) << 32) | (unsigned)(base + lane * 2);
        }
        {
            float kf = (s1 > 0.5f) ? -s1 : __builtin_inff();
            sm.nms.lkey[lane * 2 + 1] =
                ((unsigned long long)fkey(kf) << 32) | (unsigned)(base + lane * 2 + 1);
        }
    }
    __syncthreads();

    unsigned long long key0 = sm.nms.lkey[lane];
    int lab0 = sm.nms.llab[lane >> 1];
    bool v0 = ((unsigned)(key0 >> 32) < 0x80000000u) && (lab0 == L);
    unsigned long long key1 = 0; bool v1 = false; int lab1 = -1;
    if (lane + 64 < KPB) {
        key1 = sm.nms.lkey[lane + 64];
        lab1 = sm.nms.llab[(lane + 64) >> 1];
        v1 = ((unsigned)(key1 >> 32) < 0x80000000u) && (lab1 == L);
    }
    unsigned long long b0 = __ballot(v0);
    unsigned long long b1 = __ballot(v1);
    int n0 = __popcll(b0);
    int n  = n0 + __popcll(b1);
    unsigned long long below = (1ull << lane) - 1ull;
    if (v0) sm.nms.mkey[__popcll(b0 & below)] = key0;
    if (v1) sm.nms.mkey[n0 + __popcll(b1 & below)] = key1;
    __syncthreads();

    if (n > 0) {
        for (int s = 0; s < 2; ++s) {
            int j = lane + s * 64;
            if (j < n) {
                unsigned long long kj = sm.nms.mkey[j];
                int rr = 0;
                for (int i2 = 0; i2 < n; ++i2) rr += (sm.nms.mkey[i2] < kj) ? 1 : 0;
                sm.nms.skey[rr] = kj;              // rank-by-count == stable sort
            }
        }
    }
    __syncthreads();

    if (n > 0) {
        float4 box0 = make_float4(0.f, 0.f, 0.f, 0.f), box1 = box0;
        int t0 = 0, t1 = 0, keep0 = 0, keep1 = 0;
        if (lane < n) {
            t0 = (int)(unsigned)sm.nms.skey[lane] - base;
            box0 = sm.nms.lbox[t0 >> 1]; keep0 = 1;
        }
        if (lane + 64 < n) {
            t1 = (int)(unsigned)sm.nms.skey[lane + 64] - base;
            box1 = sm.nms.lbox[t1 >> 1]; keep1 = 1;
        }
        for (int i = 0; i < n; ++i) {
            int srcl = i & 63;
            int ki = __shfl((i < 64) ? keep0 : keep1, srcl);
            if (ki) {
                float4 s4 = (i < 64) ? box0 : box1;
                float4 bi;
                bi.x = __shfl(s4.x, srcl); bi.y = __shfl(s4.y, srcl);
                bi.z = __shfl(s4.z, srcl); bi.w = __shfl(s4.w, srcl);
                if (keep0 && lane > i)      { if (iou_rn(bi, box0) > 0.3f) keep0 = 0; }
                if (keep1 && lane + 64 > i) { if (iou_rn(bi, box1) > 0.3f) keep1 = 0; }
            }
        }
        if (keep0) sm.nms.lkeep[t0] = 1.0f;
        if (keep1) sm.nms.lkeep[t1] = 1.0f;
    }
    __syncthreads();

    if (lab0 == L) keepOrig[base + lane] = sm.nms.lkeep[lane];
    if (lane + 64 < KPB && lab1 == L) keepOrig[base + lane + 64] = sm.nms.lkeep[lane + 64];
}

// K2: 98 blocks x 64 — sum 8 rank partials, scatter all outputs (R10-verbatim).
__global__ void __launch_bounds__(64) k_scatter(
        const unsigned* __restrict__ rankPart,
        const float* __restrict__ score,
        const float* __restrict__ cellBox,
        const float* __restrict__ cellLabel,
        const float* __restrict__ keepOrig,
        float* __restrict__ out) {
    int i = blockIdx.x * 64 + (int)threadIdx.x;
    unsigned r = 0;
    #pragma unroll
    for (int jt = 0; jt < NJT; ++jt) r += rankPart[jt * NCAND + i];
    int cell = i >> 1;
    out[r] = (float)(i / KPB);                     // batch id
    float4 bx = *(const float4*)(cellBox + cell * 4);
    *(float4*)(out + NCAND + r * 4) = bx;
    out[NCAND * 5 + r] = cellLabel[cell];
    out[NCAND * 6 + r] = score[i];
    out[NCAND * 7 + r] = keepOrig[i];
}

extern "C" void kernel_launch(void* const* d_in, const int* in_sizes, int n_in,
                              void* d_out, int out_size, void* d_ws, size_t ws_size,
                              hipStream_t stream) {
    const float* in = (const float*)d_in[0];
    char* ws = (char*)d_ws;
    float*    score     = (float*)(ws + WS_SCORE);
    float*    cellBox   = (float*)(ws + WS_CELLBOX);
    float*    cellLabel = (float*)(ws + WS_CELLLAB);
    float*    keepOrig  = (float*)(ws + WS_KEEP);
    unsigned* rankPart  = (unsigned*)(ws + WS_RANKP);
    float* out = (float*)d_out;

    k_main<<<NBLK_K1, 64, 0, stream>>>(in, score, cellBox, cellLabel, keepOrig, rankPart);
    k_scatter<<<NCAND / 64, 64, 0, stream>>>(rankPart, score, cellBox, cellLabel,
                                             keepOrig, out);
}

// Round 16
// 23.436 us; speedup vs baseline: 1.5333x; 1.3147x over previous
//
#include <hip/hip_runtime.h>
#include <stdint.h>

#define NUM_BBOX    2
#define NUM_CLASSES 20
#define NUM_GRID    7
#define BATCH       64
#define NCELL  (BATCH * NUM_GRID * NUM_GRID)   // 3136
#define NCAND  (NCELL * NUM_BBOX)              // 6272
#define NGROUP (BATCH * NUM_CLASSES)           // 1280
#define MAXG   98
#define CPB    49                              // cells per batch
#define KPB    98                              // candidates per batch
#define NJT    8
#define JTILE  (NCAND / NJT)                   // 784 candidates per j-tile
#define JCELLS (JTILE / 2)                     // 392 cells per j-tile

#define NDECB   49                             // decode blocks (49*64 = 3136 cells)
#define B_RANK0 NDECB                          // rank blocks [49, 833)
#define B_NMS0  (NDECB + 784)                  // nms blocks  [833, 2113)
#define NBLK_K1 (NDECB + 784 + NGROUP)         // 2113

// ---- workspace layout (bytes) ----
#define WS_SCORE     0         // f32[6272]            25088
#define WS_CELLBOX   25088     // f32[3136*4]          50176
#define WS_CELLLAB   75264     // f32[3136]            12544
#define WS_KEEP      87808     // f32[6272]            25088
#define WS_RANKP     112896    // u32[8*6272]         200704

// monotone float -> sortable u32 (ascending float == ascending u32)
__device__ __forceinline__ unsigned fkey(float f) {
    unsigned u = __float_as_uint(f);
    return (u & 0x80000000u) ? ~u : (u | 0x80000000u);
}

// score of one bbox slice q[0..25): conf * max cls prob, mul-then-max chain
__device__ __forceinline__ float cand_score(const float* q) {
    float conf = q[4];
    float m = __fmul_rn(q[5], conf);
    #pragma unroll
    for (int k = 1; k < NUM_CLASSES; ++k)
        m = fmaxf(m, __fmul_rn(q[5 + k], conf));
    return m;
}

__device__ __forceinline__ float iou_rn(float4 a, float4 b) {
    float xx1 = fmaxf(a.x, b.x), yy1 = fmaxf(a.y, b.y);
    float xx2 = fminf(a.z, b.z), yy2 = fminf(a.w, b.w);
    float w = fmaxf(__fsub_rn(xx2, xx1), 0.0f);
    float h = fmaxf(__fsub_rn(yy2, yy1), 0.0f);
    float inter = __fmul_rn(w, h);
    float aa = __fmul_rn(__fsub_rn(a.z, a.x), __fsub_rn(a.w, a.y));
    float ab = __fmul_rn(__fsub_rn(b.z, b.x), __fsub_rn(b.w, b.y));
    float denom = __fadd_rn(__fsub_rn(__fadd_rn(aa, ab), inter), 1e-9f);
    return __fdiv_rn(inter, denom);
}

// Union kernel: 2113 independent blocks x 64 lanes.
//  [0,49):    decode  -> score, cellBox, cellLabel   (sole writer)
//  [49,833):  rank    -> rankPart[jt][i]             (sole writer, plain stores;
//             keys for i-tile and j-tile recomputed from input)
//  [833,2113):nms     -> keepOrig                    (sole writer; redundant
//             per-batch decode, disjoint-complete keep ownership)
__global__ void __launch_bounds__(64) k_main(
        const float* __restrict__ in,
        float* __restrict__ score,
        float* __restrict__ cellBox,
        float* __restrict__ cellLabel,
        float* __restrict__ keepOrig,
        unsigned* __restrict__ rankPart) {
    __shared__ union SMem {
        unsigned long long jkey[JTILE];            // rank branch (6272 B)
        struct {                                   // nms branch (~13.5 KB)
            float2 raw2[1225];
            unsigned long long lkey[KPB];
            float4 lbox[CPB];
            int    llab[CPB];
            float  lkeep[KPB];
            unsigned long long mkey[KPB];
            unsigned long long skey[KPB];
        } nms;
    } sm;

    const int bid  = (int)blockIdx.x;
    const int lane = (int)threadIdx.x;

    // ---------------- decode blocks ----------------
    if (bid < NDECB) {
        int cell = bid * 64 + lane;                // covers 3136 exactly
        const float* p = in + cell * 50;
        float s0 = cand_score(p);
        float s1 = cand_score(p + 25);
        int best = (s1 > s0) ? 1 : 0;              // first-occurrence argmax
        const float* q = p + best * 25;

        int lab = 0; float bv = q[5];
        #pragma unroll
        for (int k = 1; k < NUM_CLASSES; ++k)
            if (q[5 + k] > bv) { bv = q[5 + k]; lab = k; }

        int rc = cell % (NUM_GRID * NUM_GRID);
        int r = rc / NUM_GRID, c = rc % NUM_GRID;
        float x  = __fdiv_rn(__fadd_rn(q[0], (float)r), 7.0f);
        float y  = __fdiv_rn(__fadd_rn(q[1], (float)c), 7.0f);
        float hw = __fmul_rn(q[2], 0.5f);
        float hh = __fmul_rn(q[3], 0.5f);
        *(float4*)(cellBox + cell * 4) =
            make_float4(__fsub_rn(x, hw), __fsub_rn(y, hh),
                        __fadd_rn(x, hw), __fadd_rn(y, hh));
        cellLabel[cell] = (float)(lab + 1);
        score[cell * 2 + 0] = s0;
        score[cell * 2 + 1] = s1;
        return;
    }

    // ---------------- rank blocks ----------------
    if (bid < B_NMS0) {
        int rb = bid - B_RANK0;
        int ib = rb >> 3;                          // 0..97
        int jt = rb & 7;                           // 0..7

        // cooperative keys-only decode of the j-tile into LDS
        for (int cl = lane; cl < JCELLS; cl += 64) {
            int cell = jt * JCELLS + cl;
            const float* p = in + cell * 50;
            #pragma unroll
            for (int bb = 0; bb < 2; ++bb) {
                float s = cand_score(p + bb * 25);
                bool valid = s > 0.5f;
                float kf = valid ? -s : __builtin_inff();
                sm.jkey[cl * 2 + bb] =
                    ((unsigned long long)fkey(kf) << 32) | (unsigned)(cell * 2 + bb);
            }
        }
        // own key
        int i = ib * 64 + lane;
        unsigned long long my;
        {
            const float* q = in + (i >> 1) * 50 + (i & 1) * 25;
            float s = cand_score(q);
            bool valid = s > 0.5f;
            float kf = valid ? -s : __builtin_inff();
            my = ((unsigned long long)fkey(kf) << 32) | (unsigned)i;
        }
        __syncthreads();

        unsigned r = 0;
        #pragma unroll 8
        for (int j = 0; j < JTILE; ++j)
            r += (sm.jkey[j] < my) ? 1u : 0u;
        rankPart[jt * NCAND + i] = r;              // plain store, sole writer
        return;
    }

    // ---------------- nms blocks ----------------
    int g = bid - B_NMS0;
    int b = g / NUM_CLASSES;
    int L = g % NUM_CLASSES + 1;
    int base = b * KPB;

    const float2* src = (const float2*)(in + b * (CPB * 50));
    for (int t = lane; t < 1225; t += 64) sm.nms.raw2[t] = src[t];
    sm.nms.lkeep[lane] = 0.0f;
    if (lane + 64 < KPB) sm.nms.lkeep[lane + 64] = 0.0f;
    __syncthreads();

    if (lane < CPB) {
        const float* p = (const float*)sm.nms.raw2 + lane * 50;
        float s0 = cand_score(p);
        float s1 = cand_score(p + 25);
        int best = (s1 > s0) ? 1 : 0;
        const float* q = p + best * 25;

        int lab = 0; float bv = q[5];
        #pragma unroll
        for (int k = 1; k < NUM_CLASSES; ++k)
            if (q[5 + k] > bv) { bv = q[5 + k]; lab = k; }

        int r = lane / NUM_GRID, c = lane % NUM_GRID;
        float x  = __fdiv_rn(__fadd_rn(q[0], (float)r), 7.0f);
        float y  = __fdiv_rn(__fadd_rn(q[1], (float)c), 7.0f);
        float hw = __fmul_rn(q[2], 0.5f);
        float hh = __fmul_rn(q[3], 0.5f);
        sm.nms.lbox[lane] = make_float4(__fsub_rn(x, hw), __fsub_rn(y, hh),
                                        __fadd_rn(x, hw), __fadd_rn(y, hh));
        sm.nms.llab[lane] = lab + 1;
        {
            bool valid = s0 > 0.5f;
            float kf = valid ? -s0 : __builtin_inff();
            sm.nms.lkey[lane * 2] =
                ((unsigned long long)fkey(kf) << 32) | (unsigned)(base + lane * 2);
        }
        {
            bool valid = s1 > 0.5f;
            float kf = valid ? -s1 : __builtin_inff();
            sm.nms.lkey[lane * 2 + 1] =
                ((unsigned long long)fkey(kf) << 32) | (unsigned)(base + lane * 2 + 1);
        }
    }
    __syncthreads();

    unsigned long long key0 = sm.nms.lkey[lane];
    int lab0 = sm.nms.llab[lane >> 1];
    bool v0 = ((unsigned)(key0 >> 32) < 0x80000000u) && (lab0 == L);
    unsigned long long key1 = 0; bool v1 = false; int lab1 = -1;
    if (lane + 64 < KPB) {
        key1 = sm.nms.lkey[lane + 64];
        lab1 = sm.nms.llab[(lane + 64) >> 1];
        v1 = ((unsigned)(key1 >> 32) < 0x80000000u) && (lab1 == L);
    }
    unsigned long long b0 = __ballot(v0);
    unsigned long long b1 = __ballot(v1);
    int n0 = __popcll(b0);
    int n  = n0 + __popcll(b1);
    unsigned long long below = (1ull << lane) - 1ull;
    if (v0) sm.nms.mkey[__popcll(b0 & below)] = key0;
    if (v1) sm.nms.mkey[n0 + __popcll(b1 & below)] = key1;
    __syncthreads();

    if (n > 0) {
        for (int s = 0; s < 2; ++s) {
            int j = lane + s * 64;
            if (j < n) {
                unsigned long long kj = sm.nms.mkey[j];
                int rr = 0;
                for (int i2 = 0; i2 < n; ++i2) rr += (sm.nms.mkey[i2] < kj) ? 1 : 0;
                sm.nms.skey[rr] = kj;              // rank-by-count == stable sort
            }
        }
    }
    __syncthreads();

    if (n > 0) {
        float4 box0 = make_float4(0.f, 0.f, 0.f, 0.f), box1 = box0;
        int t0 = 0, t1 = 0, keep0 = 0, keep1 = 0;
        if (lane < n) {
            t0 = (int)(unsigned)sm.nms.skey[lane] - base;
            box0 = sm.nms.lbox[t0 >> 1];
            keep0 = 1;
        }
        if (lane + 64 < n) {
            t1 = (int)(unsigned)sm.nms.skey[lane + 64] - base;
            box1 = sm.nms.lbox[t1 >> 1];
            keep1 = 1;
        }
        for (int i = 0; i < n; ++i) {
            int srcl = i & 63;
            int ki = __shfl((i < 64) ? keep0 : keep1, srcl);
            if (ki) {
                float4 s4 = (i < 64) ? box0 : box1;
                float4 bi;
                bi.x = __shfl(s4.x, srcl);
                bi.y = __shfl(s4.y, srcl);
                bi.z = __shfl(s4.z, srcl);
                bi.w = __shfl(s4.w, srcl);
                if (keep0 && lane > i)      { if (iou_rn(bi, box0) > 0.3f) keep0 = 0; }
                if (keep1 && lane + 64 > i) { if (iou_rn(bi, box1) > 0.3f) keep1 = 0; }
            }
        }
        if (keep0) sm.nms.lkeep[t0] = 1.0f;
        if (keep1) sm.nms.lkeep[t1] = 1.0f;
    }
    __syncthreads();

    // keep for exactly this block's label (disjoint-complete across blocks)
    if (lab0 == L) keepOrig[base + lane] = sm.nms.lkeep[lane];
    if (lane + 64 < KPB && lab1 == L) keepOrig[base + lane + 64] = sm.nms.lkeep[lane + 64];
}

// 98 blocks x 64: sum the 8 rank partials, scatter all outputs.
__global__ void __launch_bounds__(64) k_scatter(
        const unsigned* __restrict__ rankPart,
        const float* __restrict__ score,
        const float* __restrict__ cellBox,
        const float* __restrict__ cellLabel,
        const float* __restrict__ keepOrig,
        float* __restrict__ out) {
    int i = blockIdx.x * 64 + (int)threadIdx.x;
    unsigned r = 0;
    #pragma unroll
    for (int jt = 0; jt < NJT; ++jt) r += rankPart[jt * NCAND + i];
    int cell = i >> 1;
    out[r] = (float)(i / 98);                      // batch id
    float4 bx = *(const float4*)(cellBox + cell * 4);
    *(float4*)(out + NCAND + r * 4) = bx;
    out[NCAND * 5 + r] = cellLabel[cell];
    out[NCAND * 6 + r] = score[i];
    out[NCAND * 7 + r] = keepOrig[i];
}

extern "C" void kernel_launch(void* const* d_in, const int* in_sizes, int n_in,
                              void* d_out, int out_size, void* d_ws, size_t ws_size,
                              hipStream_t stream) {
    const float* in = (const float*)d_in[0];
    char* ws = (char*)d_ws;
    float*    score     = (float*)(ws + WS_SCORE);
    float*    cellBox   = (float*)(ws + WS_CELLBOX);
    float*    cellLabel = (float*)(ws + WS_CELLLAB);
    float*    keepOrig  = (float*)(ws + WS_KEEP);
    unsigned* rankPart  = (unsigned*)(ws + WS_RANKP);
    float* out = (float*)d_out;

    k_main<<<NBLK_K1, 64, 0, stream>>>(in, score, cellBox, cellLabel, keepOrig, rankPart);
    k_scatter<<<NCAND / 64, 64, 0, stream>>>(rankPart, score, cellBox, cellLabel,
                                             keepOrig, out);
}